// Round 12
// baseline (5575.437 us; speedup 1.0000x reference)
//
#include <hip/hip_runtime.h>
#include <cmath>

// IDIM=256, CDIM=512, NH=2, N=128, M=64, T=64, BSZ=128
// x(t) = [emb(256) | reads0(64) | reads1(64) | h(512)], K=896, gate rows 2048.
// R12 = R11 + NON-TEMPORAL partials traffic (store in k_gates, load in k_fused)
// so the streaming 16MB/step bypasses L2 -> proj replicas + gates W stay
// L2-resident per XCD (resident set ~2.7MB < 4MB).
//
// ---- ws float offsets ----
#define WS_EMBT  0                       // 2,097,152  [64 t][64 k4][128 b][4]
#define WS_STATE 2097152                 //    81,920  [160 ks][128 b][4]
#define WS_C     2179072                 //    65,536  c[b][512]
#define WS_MEM   2244608                 // 1,048,576  mem[b][128][64]
#define WS_RW    3293184                 //    32,768  [hi][b][128]
#define WS_WWS   3325952                 //    32,768
#define WS_PART  3358720                 // 2,097,152  partials [8 kz][128 b][2048 row]
#define WS_WREP  5455872                 // 2,228,224  [8 rep][128 k4][544 j] float4
// total 7,684,096 floats (~30.7 MB)

#define GATES_LDS_BYTES ((3584 + 14336) * 4)   // W 14KB + x 57.3KB = 71.7KB

// direct global->LDS 16B DMA; lds base wave-uniform (lane i -> base + i*16).
#define GLD16(g, l) __builtin_amdgcn_global_load_lds( \
    (const __attribute__((address_space(1))) void*)(g), \
    (__attribute__((address_space(3))) void*)(l), 16, 0, 0)

__device__ __forceinline__ float sigm(float x) { return 1.0f / (1.0f + expf(-x)); }
__device__ __forceinline__ float softplusf(float x) {
    return fmaxf(x, 0.0f) + log1pf(expf(-fabsf(x)));
}
__device__ __forceinline__ float projbias(int j, const float* br, const float* bw) {
    int hi = j >= 268, q = j - hi * 268;
    return (q < 70) ? br[hi * 70 + q] : bw[hi * 198 + (q - 70)];
}

// ---------------- one-time: transpose embs to k-major f4-packed ----------------
__global__ __launch_bounds__(256) void k_embT(const float* __restrict__ embs,
                                              float* __restrict__ ws)
{
    int f4 = blockIdx.x * 256 + threadIdx.x;        // 524288 float4s
    int k4 = f4 & 63, b = (f4 >> 6) & 127, t = f4 >> 13;
    float4 v = *(const float4*)&embs[(size_t)(t * 128 + b) * 256 + k4 * 4];
    *(float4*)&ws[WS_EMBT + ((size_t)(t * 64 + k4) * 128 + b) * 4] = v;
}

// ---------------- one-time: build 8 per-XCD k-major proj-weight replicas ------
__global__ __launch_bounds__(256) void k_wrep(const float* __restrict__ Wr,
                                              const float* __restrict__ Ww,
                                              float* __restrict__ ws)
{
    int i = blockIdx.x * 256 + threadIdx.x;         // 557,056 float4s
    int k4 = i & 127;
    int rj = i >> 7;
    int j = rj % 544;
    float4 v = make_float4(0.f, 0.f, 0.f, 0.f);
    if (j < 536) {
        int hi = j >= 268, q = j - hi * 268;
        const float* src = (q < 70) ? &Wr[(size_t)(hi * 70 + q) * 512 + k4 * 4]
                                    : &Ww[(size_t)(hi * 198 + (q - 70)) * 512 + k4 * 4];
        v = *(const float4*)src;
    }
    int rep = rj / 544;
    ((float4*)(ws + WS_WREP))[((size_t)rep * 128 + k4) * 544 + j] = v;
}

// ---------------- one-time: init state ----------------
__global__ __launch_bounds__(256) void k_init(float* __restrict__ ws,
                                              const float* __restrict__ mem_bias,
                                              const float* __restrict__ h0,
                                              const float* __restrict__ c0,
                                              const float* __restrict__ r0)
{
    int i = blockIdx.x * 256 + threadIdx.x;          // 1,261,568 total
    if (i < 81920) {                                  // stateT
        int ks = i >> 9, c4 = i & 3;
        int k = ks * 4 + c4;
        ws[WS_STATE + i] = (ks < 32) ? r0[k] : h0[k - 128];
        return;
    }
    int j = i - 81920;
    if (j < 65536) { ws[WS_C + j] = c0[j & 511]; return; }         // c[b][ch]
    j -= 65536;
    if (j < 1048576) { ws[WS_MEM + j] = mem_bias[j & 8191]; return; }
    j -= 1048576;
    ws[WS_RW + j] = 0.0f;                                          // rw + wws
}

// ---------------- gates GEMV-GEMM (store layout [kz][b][row]) ----------------
// grid 512 = 64 row-tiles(32) x 8 k-chunks(112); 256 thr; 2 blocks/CU.
__global__ void __launch_bounds__(256, 2) k_gates(
    const float* __restrict__ W_ih,   // (2048,384)
    const float* __restrict__ W_hh,   // (2048,512)
    const float* __restrict__ ws_c,
    float* __restrict__ partials,
    int t)
{
    extern __shared__ float sm[];
    float4* w_s4 = (float4*)sm;              // [32 rows][28 kq]
    float4* x_s4 = (float4*)(sm + 3584);     // [28 k4][128 b]

    const int tx = threadIdx.x;
    const int rt = blockIdx.x >> 3, kz = blockIdx.x & 7;
    const int r0g = rt * 32, k0 = kz * 112;
    const int lane = tx & 63, wid = tx >> 6;

    const float* embsT  = ws_c + WS_EMBT + (size_t)t * 32768;
    const float* stateT = ws_c + WS_STATE;

    // stage W: 896 f4 ([32 rows][28 kq]), slot f = it*256+tx (lane-linear)
#pragma unroll
    for (int it = 0; it < 3; ++it) {
        int f = it * 256 + tx;
        int rl = f / 28, kq = f - rl * 28;
        int kg = k0 + kq * 4, r = r0g + rl;
        const float* gp = (kg < 384) ? &W_ih[r * 384 + kg]
                                     : &W_hh[r * 512 + (kg - 384)];
        GLD16(gp, &w_s4[it * 256 + wid * 64]);
    }
    if (tx < 128) {                           // slots 768..895 (waves 0,1 only)
        int f = 768 + tx;
        int rl = f / 28, kq = f - rl * 28;
        int kg = k0 + kq * 4, r = r0g + rl;
        const float* gp = (kg < 384) ? &W_ih[r * 384 + kg]
                                     : &W_hh[r * 512 + (kg - 384)];
        GLD16(gp, &w_s4[768 + wid * 64]);
    }
    // stage x: 3584 f4 ([28 k4][128 b]), slot f = it*256+tx (lane-linear)
#pragma unroll
    for (int it = 0; it < 14; ++it) {
        int f = it * 256 + tx;
        int k4g = kz * 28 + (f >> 7);
        int b = f & 127;
        const float* gp = (k4g < 64) ? &embsT[(size_t)k4g * 512 + b * 4]
                                     : &stateT[(size_t)(k4g - 64) * 512 + b * 4];
        GLD16(gp, &x_s4[it * 256 + wid * 64]);
    }
    __syncthreads();                          // compiler drains vmcnt before barrier

    const int wr0 = wid * 8;
    float acc0[8] = {}, acc1[8] = {};
#pragma unroll 4
    for (int k4 = 0; k4 < 28; ++k4) {
        float4 xv0 = x_s4[k4 * 128 + lane];
        float4 xv1 = x_s4[k4 * 128 + 64 + lane];
#pragma unroll
        for (int r = 0; r < 8; ++r) {
            float4 wv = w_s4[(wr0 + r) * 28 + k4];
            acc0[r] += wv.x * xv0.x + wv.y * xv0.y + wv.z * xv0.z + wv.w * xv0.w;
            acc1[r] += wv.x * xv1.x + wv.y * xv1.y + wv.z * xv1.z + wv.w * xv1.w;
        }
    }
    // store [kz][b][row] NON-TEMPORAL: streaming data must not evict the
    // L2-resident gate-W / proj-replica sets. Per-b lines still fully covered.
#pragma unroll
    for (int r = 0; r < 8; ++r) {
        int row = r0g + wr0 + r;
        __builtin_nontemporal_store(acc0[r],
            &partials[(size_t)kz * 262144 + lane * 2048 + row]);
        __builtin_nontemporal_store(acc1[r],
            &partials[(size_t)kz * 262144 + (lane + 64) * 2048 + row]);
    }
}

// ---------------- fused LSTM + head-proj + NTM memory ops ----------------
// 128 blocks (one per batch) x 256 thr.
__global__ __launch_bounds__(256) void k_fused(
    const float* __restrict__ partials,  // [8 kz][128 b][2048 row]
    const float* __restrict__ b_ih,
    const float* __restrict__ b_hh,
    const float* __restrict__ br,        // (2,70)
    const float* __restrict__ bw,        // (2,198)
    const int* __restrict__ lens,
    float* __restrict__ ws,
    float* __restrict__ d_out,
    int t)
{
    const int b = blockIdx.x;
    const int tx = threadIdx.x;
    const int lane = tx & 63, wid = tx >> 6;
    const int lx = tx & 127;
    const int grp = tx >> 7;          // 0 = read head, 1 = write head

    __shared__ float mem_s[128 * 66];
    __shared__ float proj_s[544];
    __shared__ float h_s[512];
    __shared__ float wg2_s[2 * 128];
    __shared__ float wf_s[2 * 128];
    __shared__ float red_s[16];
    __shared__ float ea_s[128];
    __shared__ float rvp_s[4 * 66];

    float* memg   = ws + WS_MEM;
    float* stateT = ws + WS_STATE;
    float* rwg    = ws + WS_RW;
    float* wwsg   = ws + WS_WWS;

    // ---- stage mem[b] -> LDS ----
#pragma unroll
    for (int e = 0; e < 8; ++e) {
        int f4 = e * 256 + tx;
        int n = f4 >> 4, m4 = (f4 & 15) * 4;
        float4 v = *(const float4*)&memg[b * 8192 + f4 * 4];
        *(float2*)&mem_s[n * 66 + m4]     = make_float2(v.x, v.y);
        *(float2*)&mem_s[n * 66 + m4 + 2] = make_float2(v.z, v.w);
    }

    // ---- phase 1: LSTM pointwise for batch b (2 channels/thread) ----
    // partials loads NON-TEMPORAL (read-once stream; don't allocate in L2).
    const float* pb = partials + (size_t)b * 2048;
#pragma unroll
    for (int cc = 0; cc < 2; ++cc) {
        int ch = cc * 256 + tx;
        float g4[4];
#pragma unroll
        for (int g = 0; g < 4; ++g) {
            int r = g * 512 + ch;
            float s = b_ih[r] + b_hh[r];
#pragma unroll
            for (int kz = 0; kz < 8; ++kz)
                s += __builtin_nontemporal_load(&pb[(size_t)kz * 262144 + r]);
            g4[g] = s;
        }
        float* cp = ws + WS_C + b * 512 + ch;
        float c_old = *cp;
        float c_new = sigm(g4[1]) * c_old + sigm(g4[0]) * tanhf(g4[2]);
        float h_new = sigm(g4[3]) * tanhf(c_new);
        *cp = c_new;
        h_s[ch] = h_new;
        stateT[(32 + (ch >> 2)) * 512 + b * 4 + (ch & 3)] = h_new;
        d_out[((size_t)t * 128 + b) * 640 + ch] = h_new;
        if (lens[b] - 1 == t) {
            d_out[5242880 + b * 512 + ch] = h_new;
            d_out[5308416 + b * 512 + ch] = c_new;
        }
    }
    __syncthreads();

    // ---- phase 2: head projections, thread-per-row k-major GEMV ----
    // replica (b&7) -> XCD-local L2 (now protected by nt streaming); staggered
    // k4 start (boff) spreads any cold misses across the replica.
    {
        const float4* wrep = (const float4*)(ws + WS_WREP)
                           + (size_t)(b & 7) * 128 * 544;
        const float4* h4 = (const float4*)h_s;
        const int boff = (b >> 3) * 8;
        float a0 = 0.f, a1 = 0.f, a2 = 0.f;
#pragma unroll 8
        for (int kk = 0; kk < 128; ++kk) {
            int k4 = (kk + boff) & 127;
            float4 hv = h4[k4];
            float4 w0 = wrep[k4 * 544 + tx];
            float4 w1 = wrep[k4 * 544 + 256 + tx];
            a0 += w0.x * hv.x + w0.y * hv.y + w0.z * hv.z + w0.w * hv.w;
            a1 += w1.x * hv.x + w1.y * hv.y + w1.z * hv.z + w1.w * hv.w;
            if (tx < 32) {
                float4 w2 = wrep[k4 * 544 + 512 + tx];
                a2 += w2.x * hv.x + w2.y * hv.y + w2.z * hv.z + w2.w * hv.w;
            }
        }
        proj_s[tx] = a0 + projbias(tx, br, bw);
        if (tx + 256 < 536) proj_s[tx + 256] = a1 + projbias(tx + 256, br, bw);
        if (tx < 24)        proj_s[tx + 512] = a2 + projbias(tx + 512, br, bw);
    }
    __syncthreads();

    // ---- phase 3: NTM memory ops ----
    for (int hi = 0; hi < 2; ++hi) {
        const float* p = proj_s + hi * 268 + grp * 70;
        float* wprev_g = (grp == 0 ? rwg : wwsg) + (hi * 128 + b) * 128;

        float beta = softplusf(p[64]);
        float g = sigm(p[65]);
        float s0 = p[66], s1 = p[67], s2 = p[68];
        float sm = fmaxf(s0, fmaxf(s1, s2));
        float e0 = expf(s0 - sm), e1 = expf(s1 - sm), e2 = expf(s2 - sm);
        float sden = e0 + e1 + e2;
        s0 = e0 / sden; s1 = e1 / sden; s2 = e2 / sden;
        float gamma = 1.0f + softplusf(p[69]);

        const float* mrow = mem_s + lx * 66;
        float dot = 0.f, nm = 0.f, nk = 0.f;
#pragma unroll
        for (int m = 0; m < 64; m += 2) {
            float2 kv2 = *(const float2*)&p[m];
            float2 mv2 = *(const float2*)&mrow[m];
            float kx = kv2.x + 1e-16f, ky = kv2.y + 1e-16f;
            float mx = mv2.x + 1e-16f, my = mv2.y + 1e-16f;
            dot += mx * kx + my * ky;
            nm  += mx * mx + my * my;
            nk  += kx * kx + ky * ky;
        }
        float sim = dot / fmaxf(sqrtf(nm) * sqrtf(nk), 1e-8f);
        float z = beta * sim;

        float r = z;
#pragma unroll
        for (int d = 32; d > 0; d >>= 1) r = fmaxf(r, __shfl_xor(r, d));
        if ((tx & 63) == 0) red_s[wid] = r;
        __syncthreads();
        float zmax = fmaxf(red_s[grp * 2], red_s[grp * 2 + 1]);
        float ez = expf(z - zmax);
        r = ez;
#pragma unroll
        for (int d = 32; d > 0; d >>= 1) r += __shfl_xor(r, d);
        if ((tx & 63) == 0) red_s[8 + wid] = r;
        __syncthreads();
        float zsum = red_s[8 + grp * 2] + red_s[8 + grp * 2 + 1];
        float wc = ez / zsum;
        float wgv = g * wc + (1.f - g) * wprev_g[lx];
        wg2_s[grp * 128 + lx] = wgv;
        __syncthreads();
        float wwv = s0 * wg2_s[grp * 128 + ((lx + 127) & 127)] + s1 * wgv
                  + s2 * wg2_s[grp * 128 + ((lx + 1) & 127)];
        float wp = powf(wwv, gamma);
        r = wp;
#pragma unroll
        for (int d = 32; d > 0; d >>= 1) r += __shfl_xor(r, d);
        if ((tx & 63) == 0) red_s[wid] = r;
        __syncthreads();
        float psum = red_s[grp * 2] + red_s[grp * 2 + 1];
        float wfin = wp / (psum + 1e-16f);
        wf_s[grp * 128 + lx] = wfin;
        wprev_g[lx] = wfin;
        __syncthreads();

        {
            int m = tx & 63, p4 = tx >> 6;
            float rv = 0.f;
            const int nb = p4 * 32;
#pragma unroll
            for (int n8 = 0; n8 < 32; ++n8) {
                int n = nb + n8;
                rv += wf_s[n] * mem_s[n * 66 + m];
            }
            rvp_s[p4 * 66 + m] = rv;
        }
        if (tx < 64)        ea_s[tx] = sigm(proj_s[hi * 268 + 140 + tx]);
        else if (tx < 128)  ea_s[tx] = proj_s[hi * 268 + 204 + (tx - 64)];
        __syncthreads();

        if (tx < 64) {
            float rvf = rvp_s[tx] + rvp_s[66 + tx] + rvp_s[132 + tx] + rvp_s[198 + tx];
            stateT[((hi * 64 + tx) >> 2) * 512 + b * 4 + (tx & 3)] = rvf;
            d_out[((size_t)t * 128 + b) * 640 + 512 + hi * 64 + tx] = rvf;
        }
#pragma unroll
        for (int e = 0; e < 16; ++e) {
            int f = e * 256 + tx;
            int n = f >> 5, m2 = (f & 31) * 2;
            float w2 = wf_s[128 + n];
            float2 mv = *(const float2*)&mem_s[n * 66 + m2];
            mv.x = mv.x * (1.f - w2 * ea_s[m2])     + w2 * ea_s[64 + m2];
            mv.y = mv.y * (1.f - w2 * ea_s[m2 + 1]) + w2 * ea_s[65 + m2];
            *(float2*)&mem_s[n * 66 + m2] = mv;
            if (hi == 1) *(float2*)&memg[b * 8192 + f * 2] = mv;
        }
        __syncthreads();
    }
}

// ---------------- host ----------------
extern "C" void kernel_launch(void* const* d_in, const int* in_sizes, int n_in,
                              void* d_out, int out_size, void* d_ws, size_t ws_size,
                              hipStream_t stream)
{
    (void)in_sizes; (void)n_in; (void)out_size; (void)ws_size;
    const float* embs     = (const float*)d_in[0];
    const int*   lens     = (const int*)  d_in[1];
    const float* mem_bias = (const float*)d_in[2];
    const float* W_ih     = (const float*)d_in[3];
    const float* W_hh     = (const float*)d_in[4];
    const float* b_ih     = (const float*)d_in[5];
    const float* b_hh     = (const float*)d_in[6];
    const float* Wr       = (const float*)d_in[7];
    const float* br       = (const float*)d_in[8];
    const float* Ww       = (const float*)d_in[9];
    const float* bw       = (const float*)d_in[10];
    const float* h0       = (const float*)d_in[11];
    const float* c0       = (const float*)d_in[12];
    const float* r0       = (const float*)d_in[13];
    float* out = (float*)d_out;
    float* ws  = (float*)d_ws;
    float* partials = ws + WS_PART;

    hipFuncSetAttribute(reinterpret_cast<const void*>(&k_gates),
                        hipFuncAttributeMaxDynamicSharedMemorySize, GATES_LDS_BYTES);

    k_embT<<<2048, 256, 0, stream>>>(embs, ws);
    k_wrep<<<2176, 256, 0, stream>>>(Wr, Ww, ws);
    k_init<<<4928, 256, 0, stream>>>(ws, mem_bias, h0, c0, r0);
    for (int t = 0; t < 64; ++t) {
        k_gates<<<512, 256, GATES_LDS_BYTES, stream>>>(W_ih, W_hh, ws, partials, t);
        k_fused<<<128, 256, 0, stream>>>(partials, b_ih, b_hh, br, bw,
                                         lens, ws, out, t);
    }
}

// Round 13
// 3339.233 us; speedup vs baseline: 1.6697x; 1.6697x over previous
//
#include <hip/hip_runtime.h>
#include <cmath>

// IDIM=256, CDIM=512, NH=2, N=128, M=64, T=64, BSZ=128
// R13 = R11 + (a) k_gates float4 partials stores (nt-store REVERTED: scattered
// stores need L2 write-combining; R12's nt-store caused 12x write amplification),
// (b) nt-LOADS kept on partials (protects L2-resident replicas), (c) k_fused at
// 512 threads (8 waves/CU) to hide proj/LSTM latency.
//
// ---- ws float offsets ----
#define WS_EMBT  0                       // 2,097,152  [64 t][64 k4][128 b][4]
#define WS_STATE 2097152                 //    81,920  [160 ks][128 b][4]
#define WS_C     2179072                 //    65,536  c[b][512]
#define WS_MEM   2244608                 // 1,048,576  mem[b][128][64]
#define WS_RW    3293184                 //    32,768  [hi][b][128]
#define WS_WWS   3325952                 //    32,768
#define WS_PART  3358720                 // 2,097,152  partials [8 kz][128 b][2048 row]
#define WS_WREP  5455872                 // 2,228,224  [8 rep][128 k4][544 j] float4
// total 7,684,096 floats (~30.7 MB)

#define GATES_LDS_BYTES ((3584 + 14336) * 4)   // W 14KB + x 57.3KB = 71.7KB

#define GLD16(g, l) __builtin_amdgcn_global_load_lds( \
    (const __attribute__((address_space(1))) void*)(g), \
    (__attribute__((address_space(3))) void*)(l), 16, 0, 0)

__device__ __forceinline__ float sigm(float x) { return 1.0f / (1.0f + expf(-x)); }
__device__ __forceinline__ float softplusf(float x) {
    return fmaxf(x, 0.0f) + log1pf(expf(-fabsf(x)));
}
__device__ __forceinline__ float projbias(int j, const float* br, const float* bw) {
    int hi = j >= 268, q = j - hi * 268;
    return (q < 70) ? br[hi * 70 + q] : bw[hi * 198 + (q - 70)];
}

// ---------------- one-time: transpose embs to k-major f4-packed ----------------
__global__ __launch_bounds__(256) void k_embT(const float* __restrict__ embs,
                                              float* __restrict__ ws)
{
    int f4 = blockIdx.x * 256 + threadIdx.x;        // 524288 float4s
    int k4 = f4 & 63, b = (f4 >> 6) & 127, t = f4 >> 13;
    float4 v = *(const float4*)&embs[(size_t)(t * 128 + b) * 256 + k4 * 4];
    *(float4*)&ws[WS_EMBT + ((size_t)(t * 64 + k4) * 128 + b) * 4] = v;
}

// ---------------- one-time: build 8 per-XCD k-major proj-weight replicas ------
__global__ __launch_bounds__(256) void k_wrep(const float* __restrict__ Wr,
                                              const float* __restrict__ Ww,
                                              float* __restrict__ ws)
{
    int i = blockIdx.x * 256 + threadIdx.x;         // 557,056 float4s
    int k4 = i & 127;
    int rj = i >> 7;
    int j = rj % 544;
    float4 v = make_float4(0.f, 0.f, 0.f, 0.f);
    if (j < 536) {
        int hi = j >= 268, q = j - hi * 268;
        const float* src = (q < 70) ? &Wr[(size_t)(hi * 70 + q) * 512 + k4 * 4]
                                    : &Ww[(size_t)(hi * 198 + (q - 70)) * 512 + k4 * 4];
        v = *(const float4*)src;
    }
    int rep = rj / 544;
    ((float4*)(ws + WS_WREP))[((size_t)rep * 128 + k4) * 544 + j] = v;
}

// ---------------- one-time: init state ----------------
__global__ __launch_bounds__(256) void k_init(float* __restrict__ ws,
                                              const float* __restrict__ mem_bias,
                                              const float* __restrict__ h0,
                                              const float* __restrict__ c0,
                                              const float* __restrict__ r0)
{
    int i = blockIdx.x * 256 + threadIdx.x;          // 1,261,568 total
    if (i < 81920) {                                  // stateT
        int ks = i >> 9, c4 = i & 3;
        int k = ks * 4 + c4;
        ws[WS_STATE + i] = (ks < 32) ? r0[k] : h0[k - 128];
        return;
    }
    int j = i - 81920;
    if (j < 65536) { ws[WS_C + j] = c0[j & 511]; return; }         // c[b][ch]
    j -= 65536;
    if (j < 1048576) { ws[WS_MEM + j] = mem_bias[j & 8191]; return; }
    j -= 1048576;
    ws[WS_RW + j] = 0.0f;                                          // rw + wws
}

// ---------------- gates GEMV-GEMM (store layout [kz][b][row]) ----------------
// grid 512 = 64 row-tiles(32) x 8 k-chunks(112); 256 thr; 2 blocks/CU.
__global__ void __launch_bounds__(256, 2) k_gates(
    const float* __restrict__ W_ih,   // (2048,384)
    const float* __restrict__ W_hh,   // (2048,512)
    const float* __restrict__ ws_c,
    float* __restrict__ partials,
    int t)
{
    extern __shared__ float sm[];
    float4* w_s4 = (float4*)sm;              // [32 rows][28 kq]
    float4* x_s4 = (float4*)(sm + 3584);     // [28 k4][128 b]

    const int tx = threadIdx.x;
    const int rt = blockIdx.x >> 3, kz = blockIdx.x & 7;
    const int r0g = rt * 32, k0 = kz * 112;
    const int lane = tx & 63, wid = tx >> 6;

    const float* embsT  = ws_c + WS_EMBT + (size_t)t * 32768;
    const float* stateT = ws_c + WS_STATE;

    // stage W: 896 f4 ([32 rows][28 kq]), slot f = it*256+tx (lane-linear)
#pragma unroll
    for (int it = 0; it < 3; ++it) {
        int f = it * 256 + tx;
        int rl = f / 28, kq = f - rl * 28;
        int kg = k0 + kq * 4, r = r0g + rl;
        const float* gp = (kg < 384) ? &W_ih[r * 384 + kg]
                                     : &W_hh[r * 512 + (kg - 384)];
        GLD16(gp, &w_s4[it * 256 + wid * 64]);
    }
    if (tx < 128) {                           // slots 768..895 (waves 0,1 only)
        int f = 768 + tx;
        int rl = f / 28, kq = f - rl * 28;
        int kg = k0 + kq * 4, r = r0g + rl;
        const float* gp = (kg < 384) ? &W_ih[r * 384 + kg]
                                     : &W_hh[r * 512 + (kg - 384)];
        GLD16(gp, &w_s4[768 + wid * 64]);
    }
    // stage x: 3584 f4 ([28 k4][128 b]), slot f = it*256+tx (lane-linear)
#pragma unroll
    for (int it = 0; it < 14; ++it) {
        int f = it * 256 + tx;
        int k4g = kz * 28 + (f >> 7);
        int b = f & 127;
        const float* gp = (k4g < 64) ? &embsT[(size_t)k4g * 512 + b * 4]
                                     : &stateT[(size_t)(k4g - 64) * 512 + b * 4];
        GLD16(gp, &x_s4[it * 256 + wid * 64]);
    }
    __syncthreads();

    const int wr0 = wid * 8;
    float acc0[8] = {}, acc1[8] = {};
#pragma unroll 4
    for (int k4 = 0; k4 < 28; ++k4) {
        float4 xv0 = x_s4[k4 * 128 + lane];
        float4 xv1 = x_s4[k4 * 128 + 64 + lane];
#pragma unroll
        for (int r = 0; r < 8; ++r) {
            float4 wv = w_s4[(wr0 + r) * 28 + k4];
            acc0[r] += wv.x * xv0.x + wv.y * xv0.y + wv.z * xv0.z + wv.w * xv0.w;
            acc1[r] += wv.x * xv1.x + wv.y * xv1.y + wv.z * xv1.z + wv.w * xv1.w;
        }
    }
    // store [kz][b][row] as float4 (rows consecutive per thread). Plain stores:
    // L2 write-combines the per-b lines (R12's nt-store amplified 12x).
    {
        size_t base = (size_t)kz * 262144 + r0g + wr0;
        *(float4*)&partials[base + lane * 2048] =
            make_float4(acc0[0], acc0[1], acc0[2], acc0[3]);
        *(float4*)&partials[base + lane * 2048 + 4] =
            make_float4(acc0[4], acc0[5], acc0[6], acc0[7]);
        *(float4*)&partials[base + (lane + 64) * 2048] =
            make_float4(acc1[0], acc1[1], acc1[2], acc1[3]);
        *(float4*)&partials[base + (lane + 64) * 2048 + 4] =
            make_float4(acc1[4], acc1[5], acc1[6], acc1[7]);
    }
}

// ---------------- fused LSTM + head-proj + NTM memory ops ----------------
// 128 blocks (one per batch) x 512 thr (8 waves/CU for latency hiding).
// Phase 3 runs all 512 threads; waves 4-7 duplicate waves 0-3's head-group
// computation with identical inputs/outputs (benign), except rvp partial sums
// which use all 8 waves productively.
__global__ __launch_bounds__(512) void k_fused(
    const float* __restrict__ partials,  // [8 kz][128 b][2048 row]
    const float* __restrict__ b_ih,
    const float* __restrict__ b_hh,
    const float* __restrict__ br,        // (2,70)
    const float* __restrict__ bw,        // (2,198)
    const int* __restrict__ lens,
    float* __restrict__ ws,
    float* __restrict__ d_out,
    int t)
{
    const int b = blockIdx.x;
    const int tx = threadIdx.x;
    const int lane = tx & 63, wid = tx >> 6;      // wid 0..7
    const int lx = tx & 127;
    const int grp = (tx >> 7) & 1;                // 0,1,0,1 per quarter

    __shared__ float mem_s[128 * 66];
    __shared__ float proj_s[544];
    __shared__ float h_s[512];
    __shared__ float wg2_s[2 * 128];
    __shared__ float wf_s[2 * 128];
    __shared__ float red_s[16];
    __shared__ float ea_s[128];
    __shared__ float rvp_s[8 * 66];

    float* memg   = ws + WS_MEM;
    float* stateT = ws + WS_STATE;
    float* rwg    = ws + WS_RW;
    float* wwsg   = ws + WS_WWS;

    // ---- stage mem[b] -> LDS ----
#pragma unroll
    for (int e = 0; e < 4; ++e) {
        int f4 = e * 512 + tx;
        int n = f4 >> 4, m4 = (f4 & 15) * 4;
        float4 v = *(const float4*)&memg[b * 8192 + f4 * 4];
        *(float2*)&mem_s[n * 66 + m4]     = make_float2(v.x, v.y);
        *(float2*)&mem_s[n * 66 + m4 + 2] = make_float2(v.z, v.w);
    }

    // ---- phase 1: LSTM pointwise, 1 channel/thread (nt loads on partials) ----
    {
        const float* pb = partials + (size_t)b * 2048;
        int ch = tx;
        float g4[4];
#pragma unroll
        for (int g = 0; g < 4; ++g) {
            int r = g * 512 + ch;
            float s = b_ih[r] + b_hh[r];
#pragma unroll
            for (int kz = 0; kz < 8; ++kz)
                s += __builtin_nontemporal_load(&pb[(size_t)kz * 262144 + r]);
            g4[g] = s;
        }
        float* cp = ws + WS_C + b * 512 + ch;
        float c_old = *cp;
        float c_new = sigm(g4[1]) * c_old + sigm(g4[0]) * tanhf(g4[2]);
        float h_new = sigm(g4[3]) * tanhf(c_new);
        *cp = c_new;
        h_s[ch] = h_new;
        stateT[(32 + (ch >> 2)) * 512 + b * 4 + (ch & 3)] = h_new;
        d_out[((size_t)t * 128 + b) * 640 + ch] = h_new;
        if (lens[b] - 1 == t) {
            d_out[5242880 + b * 512 + ch] = h_new;
            d_out[5308416 + b * 512 + ch] = c_new;
        }
    }
    __syncthreads();

    // ---- phase 2: head projections, 1 row/thread k-major GEMV ----
    {
        const float4* wrep = (const float4*)(ws + WS_WREP)
                           + (size_t)(b & 7) * 128 * 544;
        const float4* h4 = (const float4*)h_s;
        const int boff = (b >> 3) * 8;
        float a0 = 0.f, a1 = 0.f;
#pragma unroll 8
        for (int kk = 0; kk < 128; ++kk) {
            int k4 = (kk + boff) & 127;
            float4 hv = h4[k4];
            float4 w0 = wrep[k4 * 544 + tx];
            a0 += w0.x * hv.x + w0.y * hv.y + w0.z * hv.z + w0.w * hv.w;
            if (tx < 32) {
                float4 w1 = wrep[k4 * 544 + 512 + tx];
                a1 += w1.x * hv.x + w1.y * hv.y + w1.z * hv.z + w1.w * hv.w;
            }
        }
        proj_s[tx] = a0 + projbias(tx, br, bw);          // rows 0..511 (tx<512)
        if (tx < 24) proj_s[512 + tx] = a1 + projbias(512 + tx, br, bw);
    }
    __syncthreads();

    // ---- phase 3: NTM memory ops (all 512 thr; waves 4-7 duplicate-identical) --
    for (int hi = 0; hi < 2; ++hi) {
        const float* p = proj_s + hi * 268 + grp * 70;
        float* wprev_g = (grp == 0 ? rwg : wwsg) + (hi * 128 + b) * 128;

        float beta = softplusf(p[64]);
        float g = sigm(p[65]);
        float s0 = p[66], s1 = p[67], s2 = p[68];
        float sm = fmaxf(s0, fmaxf(s1, s2));
        float e0 = expf(s0 - sm), e1 = expf(s1 - sm), e2 = expf(s2 - sm);
        float sden = e0 + e1 + e2;
        s0 = e0 / sden; s1 = e1 / sden; s2 = e2 / sden;
        float gamma = 1.0f + softplusf(p[69]);

        const float* mrow = mem_s + lx * 66;
        float dot = 0.f, nm = 0.f, nk = 0.f;
#pragma unroll
        for (int m = 0; m < 64; m += 2) {
            float2 kv2 = *(const float2*)&p[m];
            float2 mv2 = *(const float2*)&mrow[m];
            float kx = kv2.x + 1e-16f, ky = kv2.y + 1e-16f;
            float mx = mv2.x + 1e-16f, my = mv2.y + 1e-16f;
            dot += mx * kx + my * ky;
            nm  += mx * mx + my * my;
            nk  += kx * kx + ky * ky;
        }
        float sim = dot / fmaxf(sqrtf(nm) * sqrtf(nk), 1e-8f);
        float z = beta * sim;

        float r = z;
#pragma unroll
        for (int d = 32; d > 0; d >>= 1) r = fmaxf(r, __shfl_xor(r, d));
        if (lane == 0) red_s[wid] = r;
        __syncthreads();
        float zmax = fmaxf(red_s[grp * 2], red_s[grp * 2 + 1]);
        float ez = expf(z - zmax);
        r = ez;
#pragma unroll
        for (int d = 32; d > 0; d >>= 1) r += __shfl_xor(r, d);
        if (lane == 0) red_s[8 + wid] = r;
        __syncthreads();
        float zsum = red_s[8 + grp * 2] + red_s[8 + grp * 2 + 1];
        float wc = ez / zsum;
        float wgv = g * wc + (1.f - g) * wprev_g[lx];
        wg2_s[grp * 128 + lx] = wgv;                 // duplicate-identical writes
        __syncthreads();
        float wwv = s0 * wg2_s[grp * 128 + ((lx + 127) & 127)] + s1 * wgv
                  + s2 * wg2_s[grp * 128 + ((lx + 1) & 127)];
        float wp = powf(wwv, gamma);
        r = wp;
#pragma unroll
        for (int d = 32; d > 0; d >>= 1) r += __shfl_xor(r, d);
        if (lane == 0) red_s[wid] = r;
        __syncthreads();
        float psum = red_s[grp * 2] + red_s[grp * 2 + 1];
        float wfin = wp / (psum + 1e-16f);
        wf_s[grp * 128 + lx] = wfin;                 // duplicate-identical
        wprev_g[lx] = wfin;                          // duplicate-identical
        __syncthreads();

        // read vector partials: all 8 waves productive (16 rows each)
        {
            int m = tx & 63, p8 = tx >> 6;
            float rv = 0.f;
            const int nb = p8 * 16;
#pragma unroll
            for (int n8 = 0; n8 < 16; ++n8) {
                int n = nb + n8;
                rv += wf_s[n] * mem_s[n * 66 + m];
            }
            rvp_s[p8 * 66 + m] = rv;
        }
        if (tx < 64)        ea_s[tx] = sigm(proj_s[hi * 268 + 140 + tx]);
        else if (tx < 128)  ea_s[tx] = proj_s[hi * 268 + 204 + (tx - 64)];
        __syncthreads();

        if (tx < 64) {
            float rvf = 0.f;
#pragma unroll
            for (int q = 0; q < 8; ++q) rvf += rvp_s[q * 66 + tx];
            stateT[((hi * 64 + tx) >> 2) * 512 + b * 4 + (tx & 3)] = rvf;
            d_out[((size_t)t * 128 + b) * 640 + 512 + hi * 64 + tx] = rvf;
        }
        // erase/add update
#pragma unroll
        for (int e = 0; e < 8; ++e) {
            int f = e * 512 + tx;
            int n = f >> 5, m2 = (f & 31) * 2;
            float w2 = wf_s[128 + n];
            float2 mv = *(const float2*)&mem_s[n * 66 + m2];
            mv.x = mv.x * (1.f - w2 * ea_s[m2])     + w2 * ea_s[64 + m2];
            mv.y = mv.y * (1.f - w2 * ea_s[m2 + 1]) + w2 * ea_s[65 + m2];
            *(float2*)&mem_s[n * 66 + m2] = mv;
            if (hi == 1) *(float2*)&memg[b * 8192 + f * 2] = mv;
        }
        __syncthreads();
    }
}

// ---------------- host ----------------
extern "C" void kernel_launch(void* const* d_in, const int* in_sizes, int n_in,
                              void* d_out, int out_size, void* d_ws, size_t ws_size,
                              hipStream_t stream)
{
    (void)in_sizes; (void)n_in; (void)out_size; (void)ws_size;
    const float* embs     = (const float*)d_in[0];
    const int*   lens     = (const int*)  d_in[1];
    const float* mem_bias = (const float*)d_in[2];
    const float* W_ih     = (const float*)d_in[3];
    const float* W_hh     = (const float*)d_in[4];
    const float* b_ih     = (const float*)d_in[5];
    const float* b_hh     = (const float*)d_in[6];
    const float* Wr       = (const float*)d_in[7];
    const float* br       = (const float*)d_in[8];
    const float* Ww       = (const float*)d_in[9];
    const float* bw       = (const float*)d_in[10];
    const float* h0       = (const float*)d_in[11];
    const float* c0       = (const float*)d_in[12];
    const float* r0       = (const float*)d_in[13];
    float* out = (float*)d_out;
    float* ws  = (float*)d_ws;
    float* partials = ws + WS_PART;

    hipFuncSetAttribute(reinterpret_cast<const void*>(&k_gates),
                        hipFuncAttributeMaxDynamicSharedMemorySize, GATES_LDS_BYTES);

    k_embT<<<2048, 256, 0, stream>>>(embs, ws);
    k_wrep<<<2176, 256, 0, stream>>>(Wr, Ww, ws);
    k_init<<<4928, 256, 0, stream>>>(ws, mem_bias, h0, c0, r0);
    for (int t = 0; t < 64; ++t) {
        k_gates<<<512, 256, GATES_LDS_BYTES, stream>>>(W_ih, W_hh, ws, partials, t);
        k_fused<<<128, 512, 0, stream>>>(partials, b_ih, b_hh, br, bw,
                                         lens, ws, out, t);
    }
}

// Round 14
// 2731.412 us; speedup vs baseline: 2.0412x; 1.2225x over previous
//
#include <hip/hip_runtime.h>
#include <cmath>

// IDIM=256, CDIM=512, NH=2, N=128, M=64, T=64, BSZ=128
// x(t) = [emb(256) | reads0(64) | reads1(64) | h(512)], K=896, gate rows 2048.
// R14 = R8 (champion, 2675us) + nt-LOADS on read-once streams (partials in
// k_lstm, part2 in k_memops) to protect L2-resident weights. Nt-stores are NOT
// used anywhere (R12 lesson: scattered nt-stores amplify writes 12x).
//
// k-major x buffers (float4-packed over k):
//   embsT  [64 t][64 k4][128 b][4]
//   stateT [160 ks][128 b][4]   ks 0..31 = reads (k 256..383), 32..159 = h
//
// ---- ws float offsets ----
#define WS_EMBT  0                       // 2,097,152
#define WS_STATE 2097152                 //    81,920
#define WS_C     2179072                 //    65,536  c[ch][b]
#define WS_MEM   2244608                 // 1,048,576  mem[b][128][64]
#define WS_RW    3293184                 //    32,768  [hi][b][128]
#define WS_WWS   3325952                 //    32,768
#define WS_PART  3358720                 // 2,097,152  partials [8][2048][128]
                                         //            part2 [8][128][544] aliases
// total 5,455,872 floats (~21.9 MB)

#define GATES_LDS_BYTES ((3584 + 14336) * 4)   // W 14KB + x 57.3KB = 71.7KB

// direct global->LDS 16B DMA; lds base must be wave-uniform (lane i lands at
// base + i*16). Slot layouts below are lane-linear by construction.
#define GLD16(g, l) __builtin_amdgcn_global_load_lds( \
    (const __attribute__((address_space(1))) void*)(g), \
    (__attribute__((address_space(3))) void*)(l), 16, 0, 0)

__device__ __forceinline__ float sigm(float x) { return 1.0f / (1.0f + expf(-x)); }
__device__ __forceinline__ float softplusf(float x) {
    return fmaxf(x, 0.0f) + log1pf(expf(-fabsf(x)));
}

// ---------------- one-time: transpose embs to k-major f4-packed ----------------
__global__ __launch_bounds__(256) void k_embT(const float* __restrict__ embs,
                                              float* __restrict__ ws)
{
    int f4 = blockIdx.x * 256 + threadIdx.x;        // 524288 float4s
    int k4 = f4 & 63, b = (f4 >> 6) & 127, t = f4 >> 13;
    float4 v = *(const float4*)&embs[(size_t)(t * 128 + b) * 256 + k4 * 4];
    *(float4*)&ws[WS_EMBT + ((size_t)(t * 64 + k4) * 128 + b) * 4] = v;
}

// ---------------- one-time: init state ----------------
__global__ __launch_bounds__(256) void k_init(float* __restrict__ ws,
                                              const float* __restrict__ mem_bias,
                                              const float* __restrict__ h0,
                                              const float* __restrict__ c0,
                                              const float* __restrict__ r0)
{
    int i = blockIdx.x * 256 + threadIdx.x;          // 1,261,568 total
    if (i < 81920) {                                  // stateT
        int ks = i >> 9, rem = i & 511, c4 = rem & 3;
        int k = ks * 4 + c4;
        ws[WS_STATE + i] = (ks < 32) ? r0[k] : h0[k - 128];
        return;
    }
    int j = i - 81920;
    if (j < 65536) { ws[WS_C + j] = c0[j >> 7]; return; }          // c[ch][b]
    j -= 65536;
    if (j < 1048576) { ws[WS_MEM + j] = mem_bias[j & 8191]; return; }
    j -= 1048576;
    ws[WS_RW + j] = 0.0f;                                          // rw + wws
}

// ---------------- gates GEMV-GEMM ----------------
// grid 512 = 64 row-tiles(32) x 8 k-chunks(112); 256 thr; 2 blocks/CU.
// wave wid: rows wid*8..wid*8+7; each lane handles batches (lane, lane+64).
// W and the x-slice staged to LDS via global_load_lds; inner loop pure LDS+FMA.
__global__ void __launch_bounds__(256, 2) k_gates(
    const float* __restrict__ W_ih,   // (2048,384)
    const float* __restrict__ W_hh,   // (2048,512)
    const float* __restrict__ ws_c,
    float* __restrict__ partials,
    int t)
{
    extern __shared__ float sm[];
    float4* w_s4 = (float4*)sm;              // [32 rows][28 kq]
    float4* x_s4 = (float4*)(sm + 3584);     // [28 k4][128 b]

    const int tx = threadIdx.x;
    const int rt = blockIdx.x >> 3, kz = blockIdx.x & 7;
    const int r0g = rt * 32, k0 = kz * 112;
    const int lane = tx & 63, wid = tx >> 6;

    const float* embsT  = ws_c + WS_EMBT + (size_t)t * 32768;
    const float* stateT = ws_c + WS_STATE;

    // stage W: 896 f4 ([32 rows][28 kq]), slot f = it*256+tx (lane-linear)
#pragma unroll
    for (int it = 0; it < 3; ++it) {
        int f = it * 256 + tx;
        int rl = f / 28, kq = f - rl * 28;
        int kg = k0 + kq * 4, r = r0g + rl;
        const float* gp = (kg < 384) ? &W_ih[r * 384 + kg]
                                     : &W_hh[r * 512 + (kg - 384)];
        GLD16(gp, &w_s4[it * 256 + wid * 64]);
    }
    if (tx < 128) {                           // slots 768..895 (waves 0,1 only)
        int f = 768 + tx;
        int rl = f / 28, kq = f - rl * 28;
        int kg = k0 + kq * 4, r = r0g + rl;
        const float* gp = (kg < 384) ? &W_ih[r * 384 + kg]
                                     : &W_hh[r * 512 + (kg - 384)];
        GLD16(gp, &w_s4[768 + wid * 64]);
    }
    // stage x: 3584 f4 ([28 k4][128 b]), slot f = it*256+tx (lane-linear)
#pragma unroll
    for (int it = 0; it < 14; ++it) {
        int f = it * 256 + tx;
        int k4g = kz * 28 + (f >> 7);
        int b = f & 127;
        const float* gp = (k4g < 64) ? &embsT[(size_t)k4g * 512 + b * 4]
                                     : &stateT[(size_t)(k4g - 64) * 512 + b * 4];
        GLD16(gp, &x_s4[it * 256 + wid * 64]);
    }
    __syncthreads();                          // compiler drains vmcnt before barrier

    const int wr0 = wid * 8;
    float acc0[8] = {}, acc1[8] = {};
#pragma unroll 4
    for (int k4 = 0; k4 < 28; ++k4) {
        float4 xv0 = x_s4[k4 * 128 + lane];
        float4 xv1 = x_s4[k4 * 128 + 64 + lane];
#pragma unroll
        for (int r = 0; r < 8; ++r) {
            float4 wv = w_s4[(wr0 + r) * 28 + k4];
            acc0[r] += wv.x * xv0.x + wv.y * xv0.y + wv.z * xv0.z + wv.w * xv0.w;
            acc1[r] += wv.x * xv1.x + wv.y * xv1.y + wv.z * xv1.z + wv.w * xv1.w;
        }
    }
#pragma unroll
    for (int r = 0; r < 8; ++r) {
        int row = r0g + wr0 + r;
        partials[(size_t)kz * 262144 + row * 128 + lane]      = acc0[r];
        partials[(size_t)kz * 262144 + row * 128 + 64 + lane] = acc1[r];
    }
}

// ---------------- LSTM pointwise ----------------
// grid 256 = 128 ch-tiles(4) x 2 batch-halves; wave w -> ch = cht*4 + w.
// partials reads are NON-TEMPORAL (read-once stream; keep W sets L2-resident).
__global__ __launch_bounds__(256) void k_lstm(
    const float* __restrict__ partials,
    const float* __restrict__ b_ih,
    const float* __restrict__ b_hh,
    float* __restrict__ ws,
    float* __restrict__ d_out,
    const int* __restrict__ lens,
    int t)
{
    const int tx = threadIdx.x;
    const int half = blockIdx.x & 1, cht = blockIdx.x >> 1;
    const int ch = cht * 4 + (tx >> 6);
    const int lane = tx & 63, b = half * 64 + lane;

    float g4[4];
#pragma unroll
    for (int g = 0; g < 4; ++g) {
        int r = g * 512 + ch;
        float s = b_ih[r] + b_hh[r];
#pragma unroll
        for (int kzq = 0; kzq < 8; ++kzq)
            s += __builtin_nontemporal_load(
                     &partials[(size_t)kzq * 262144 + r * 128 + b]);
        g4[g] = s;
    }
    float* cp = ws + WS_C + ch * 128;
    float c_old = cp[b];
    float c_new = sigm(g4[1]) * c_old + sigm(g4[0]) * tanhf(g4[2]);
    float h_new = sigm(g4[3]) * tanhf(c_new);
    cp[b] = c_new;
    ws[WS_STATE + (32 + (ch >> 2)) * 512 + b * 4 + (ch & 3)] = h_new;
    d_out[((size_t)t * 128 + b) * 640 + ch] = h_new;
    if (lens[b] - 1 == t) {
        d_out[5242880 + b * 512 + ch] = h_new;
        d_out[5308416 + b * 512 + ch] = c_new;
    }
}

// ---------------- head projections GEMV-GEMM ----------------
// grid 272 = 34 j-tiles(16) x 8 k-chunks(64); 256 thr.
// wave wid: j rows wid*4..+3; lane batches (lane, lane+64). W read exactly once
// per step across the grid (traffic-optimal shape).
__global__ __launch_bounds__(256) void k_proj(
    const float* __restrict__ ws_c,
    const float* __restrict__ Wr,     // (2,70,512)
    const float* __restrict__ Ww,     // (2,198,512)
    float* __restrict__ part2)        // [kz][b][544]
{
    __shared__ float w_s[16 * 64];        // 4KB
    __shared__ float x_s[16 * 128 * 4];   // 32KB
    float4* w_s4 = (float4*)w_s;
    float4* x_s4 = (float4*)x_s;

    const int tx = threadIdx.x;
    const int jt = blockIdx.x >> 3, kz = blockIdx.x & 7;
    const int j0 = jt * 16, k0 = kz * 64;
    const float* stateT = ws_c + WS_STATE;

    // stage W: 256 f4 (16 j x 16 kq)
    {
        int rl = tx >> 4, kq = tx & 15;
        int j = j0 + rl;
        float4 v = make_float4(0.f, 0.f, 0.f, 0.f);
        if (j < 536) {
            int hi = j >= 268, q = j - hi * 268;
            v = (q < 70) ? *(const float4*)&Wr[(hi * 70 + q) * 512 + k0 + kq * 4]
                         : *(const float4*)&Ww[(hi * 198 + (q - 70)) * 512 + k0 + kq * 4];
        }
        w_s4[tx] = v;
    }
    // stage x: 2048 f4 ([16 k4][128 b]) from h part of stateT
#pragma unroll
    for (int it = 0; it < 8; ++it) {
        int f = it * 256 + tx;
        int k4 = f >> 7, b = f & 127;
        x_s4[f] = *(const float4*)&stateT[(size_t)(32 + kz * 16 + k4) * 512 + b * 4];
    }
    __syncthreads();

    const int lane = tx & 63, wid = tx >> 6;
    const int jw0 = wid * 4;
    float acc0[4] = {}, acc1[4] = {};
#pragma unroll 4
    for (int k4 = 0; k4 < 16; ++k4) {
        float4 xv0 = x_s4[k4 * 128 + lane];
        float4 xv1 = x_s4[k4 * 128 + 64 + lane];
#pragma unroll
        for (int r = 0; r < 4; ++r) {
            float4 wv = w_s4[(jw0 + r) * 16 + k4];
            acc0[r] += wv.x * xv0.x + wv.y * xv0.y + wv.z * xv0.z + wv.w * xv0.w;
            acc1[r] += wv.x * xv1.x + wv.y * xv1.y + wv.z * xv1.z + wv.w * xv1.w;
        }
    }
#pragma unroll
    for (int r = 0; r < 4; ++r) {
        int j = j0 + jw0 + r;
        if (j < 536) {
            part2[(size_t)kz * 69632 + lane * 544 + j]        = acc0[r];
            part2[(size_t)kz * 69632 + (lane + 64) * 544 + j] = acc1[r];
        }
    }
}

// ---------------- per-batch NTM memory ops ----------------
__global__ __launch_bounds__(256) void k_memops(
    const float* __restrict__ part2,  // [8][128][544]
    const float* __restrict__ br,     // (2,70)
    const float* __restrict__ bw,     // (2,198)
    float* __restrict__ ws,
    float* __restrict__ d_out,
    int t)
{
    const int b = blockIdx.x;
    const int tx = threadIdx.x;
    const int lx = tx & 127;
    const int grp = tx >> 7;          // 0 = read head, 1 = write head
    const int wid = tx >> 6;

    __shared__ float mem_s[128 * 66];
    __shared__ float proj_s[544];
    __shared__ float wg2_s[2 * 128];
    __shared__ float wf_s[2 * 128];
    __shared__ float red_s[16];
    __shared__ float ea_s[128];
    __shared__ float rvp_s[4 * 66];

    float* memg   = ws + WS_MEM;
    float* stateT = ws + WS_STATE;
    float* rwg    = ws + WS_RW;
    float* wwsg   = ws + WS_WWS;

    // part2 gather: NON-TEMPORAL (read-once stream)
    for (int j = tx; j < 536; j += 256) {
        int hi = j >= 268, q = j - hi * 268;
        float s = (q < 70) ? br[hi * 70 + q] : bw[hi * 198 + (q - 70)];
#pragma unroll
        for (int kzq = 0; kzq < 8; ++kzq)
            s += __builtin_nontemporal_load(
                     &part2[(size_t)kzq * 69632 + b * 544 + j]);
        proj_s[j] = s;
    }
#pragma unroll
    for (int e = 0; e < 8; ++e) {
        int f4 = e * 256 + tx;
        int n = f4 >> 4, m4 = (f4 & 15) * 4;
        float4 v = *(const float4*)&memg[b * 8192 + f4 * 4];
        *(float2*)&mem_s[n * 66 + m4]     = make_float2(v.x, v.y);
        *(float2*)&mem_s[n * 66 + m4 + 2] = make_float2(v.z, v.w);
    }
    __syncthreads();

    for (int hi = 0; hi < 2; ++hi) {
        const float* p = proj_s + hi * 268 + grp * 70;
        float* wprev_g = (grp == 0 ? rwg : wwsg) + (hi * 128 + b) * 128;

        float beta = softplusf(p[64]);
        float g = sigm(p[65]);
        float s0 = p[66], s1 = p[67], s2 = p[68];
        float sm = fmaxf(s0, fmaxf(s1, s2));
        float e0 = expf(s0 - sm), e1 = expf(s1 - sm), e2 = expf(s2 - sm);
        float sden = e0 + e1 + e2;
        s0 = e0 / sden; s1 = e1 / sden; s2 = e2 / sden;
        float gamma = 1.0f + softplusf(p[69]);

        const float* mrow = mem_s + lx * 66;
        float dot = 0.f, nm = 0.f, nk = 0.f;
#pragma unroll
        for (int m = 0; m < 64; m += 2) {
            float2 kv2 = *(const float2*)&p[m];
            float2 mv2 = *(const float2*)&mrow[m];
            float kx = kv2.x + 1e-16f, ky = kv2.y + 1e-16f;
            float mx = mv2.x + 1e-16f, my = mv2.y + 1e-16f;
            dot += mx * kx + my * ky;
            nm  += mx * mx + my * my;
            nk  += kx * kx + ky * ky;
        }
        float sim = dot / fmaxf(sqrtf(nm) * sqrtf(nk), 1e-8f);
        float z = beta * sim;

        float r = z;
#pragma unroll
        for (int d = 32; d > 0; d >>= 1) r = fmaxf(r, __shfl_xor(r, d));
        if ((tx & 63) == 0) red_s[wid] = r;
        __syncthreads();
        float zmax = fmaxf(red_s[grp * 2], red_s[grp * 2 + 1]);
        float ez = expf(z - zmax);
        r = ez;
#pragma unroll
        for (int d = 32; d > 0; d >>= 1) r += __shfl_xor(r, d);
        if ((tx & 63) == 0) red_s[8 + wid] = r;
        __syncthreads();
        float zsum = red_s[8 + grp * 2] + red_s[8 + grp * 2 + 1];
        float wc = ez / zsum;
        float wgv = g * wc + (1.f - g) * wprev_g[lx];
        wg2_s[grp * 128 + lx] = wgv;
        __syncthreads();
        float wwv = s0 * wg2_s[grp * 128 + ((lx + 127) & 127)] + s1 * wgv
                  + s2 * wg2_s[grp * 128 + ((lx + 1) & 127)];
        float wp = powf(wwv, gamma);
        r = wp;
#pragma unroll
        for (int d = 32; d > 0; d >>= 1) r += __shfl_xor(r, d);
        if ((tx & 63) == 0) red_s[wid] = r;
        __syncthreads();
        float psum = red_s[grp * 2] + red_s[grp * 2 + 1];
        float wfin = wp / (psum + 1e-16f);
        wf_s[grp * 128 + lx] = wfin;
        wprev_g[lx] = wfin;
        __syncthreads();

        {
            int m = tx & 63, p4 = tx >> 6;
            float rv = 0.f;
            const int nb = p4 * 32;
#pragma unroll
            for (int n8 = 0; n8 < 32; ++n8) {
                int n = nb + n8;
                rv += wf_s[n] * mem_s[n * 66 + m];
            }
            rvp_s[p4 * 66 + m] = rv;
        }
        if (tx < 64)        ea_s[tx] = sigm(proj_s[hi * 268 + 140 + tx]);
        else if (tx < 128)  ea_s[tx] = proj_s[hi * 268 + 204 + (tx - 64)];
        __syncthreads();

        if (tx < 64) {
            float rvf = rvp_s[tx] + rvp_s[66 + tx] + rvp_s[132 + tx] + rvp_s[198 + tx];
            stateT[((hi * 64 + tx) >> 2) * 512 + b * 4 + (tx & 3)] = rvf;
            d_out[((size_t)t * 128 + b) * 640 + 512 + hi * 64 + tx] = rvf;
        }
#pragma unroll
        for (int e = 0; e < 16; ++e) {
            int f = e * 256 + tx;
            int n = f >> 5, m2 = (f & 31) * 2;
            float w2 = wf_s[128 + n];
            float2 mv = *(const float2*)&mem_s[n * 66 + m2];
            mv.x = mv.x * (1.f - w2 * ea_s[m2])     + w2 * ea_s[64 + m2];
            mv.y = mv.y * (1.f - w2 * ea_s[m2 + 1]) + w2 * ea_s[65 + m2];
            *(float2*)&mem_s[n * 66 + m2] = mv;
            if (hi == 1) *(float2*)&memg[b * 8192 + f * 2] = mv;
        }
        __syncthreads();
    }
}

// ---------------- host ----------------
extern "C" void kernel_launch(void* const* d_in, const int* in_sizes, int n_in,
                              void* d_out, int out_size, void* d_ws, size_t ws_size,
                              hipStream_t stream)
{
    (void)in_sizes; (void)n_in; (void)out_size; (void)ws_size;
    const float* embs     = (const float*)d_in[0];
    const int*   lens     = (const int*)  d_in[1];
    const float* mem_bias = (const float*)d_in[2];
    const float* W_ih     = (const float*)d_in[3];
    const float* W_hh     = (const float*)d_in[4];
    const float* b_ih     = (const float*)d_in[5];
    const float* b_hh     = (const float*)d_in[6];
    const float* Wr       = (const float*)d_in[7];
    const float* br       = (const float*)d_in[8];
    const float* Ww       = (const float*)d_in[9];
    const float* bw       = (const float*)d_in[10];
    const float* h0       = (const float*)d_in[11];
    const float* c0       = (const float*)d_in[12];
    const float* r0       = (const float*)d_in[13];
    float* out = (float*)d_out;
    float* ws  = (float*)d_ws;
    float* partials = ws + WS_PART;
    float* part2    = ws + WS_PART;

    hipFuncSetAttribute(reinterpret_cast<const void*>(&k_gates),
                        hipFuncAttributeMaxDynamicSharedMemorySize, GATES_LDS_BYTES);

    k_embT<<<2048, 256, 0, stream>>>(embs, ws);
    k_init<<<4928, 256, 0, stream>>>(ws, mem_bias, h0, c0, r0);
    for (int t = 0; t < 64; ++t) {
        k_gates<<<512, 256, GATES_LDS_BYTES, stream>>>(W_ih, W_hh, ws, partials, t);
        k_lstm<<<256, 256, 0, stream>>>(partials, b_ih, b_hh, ws, out, lens, t);
        k_proj<<<272, 256, 0, stream>>>(ws, Wr, Ww, part2);
        k_memops<<<128, 256, 0, stream>>>(part2, br, bw, ws, out, t);
    }
}